// Round 10
// baseline (160.971 us; speedup 1.0000x reference)
//
#include <hip/hip_runtime.h>
#include <stdint.h>

using short8  = __attribute__((ext_vector_type(8))) short;   // 8 bf16 = 4 VGPRs
using f32x4   = __attribute__((ext_vector_type(4))) float;
using float4v = __attribute__((ext_vector_type(4))) float;
using u16x4   = __attribute__((ext_vector_type(4))) unsigned short;

__device__ __forceinline__ unsigned short f2b(float f) {
    union { float f; unsigned int i; } v; v.f = f;
    unsigned int i = v.i;
    unsigned int r = (i + 0x7fffu + ((i >> 16) & 1u)) >> 16;   // RNE
    return (unsigned short)r;
}
__device__ __forceinline__ unsigned short f2bt(float f) {      // truncate (1 VALU)
    union { float f; unsigned int i; } v; v.f = f;
    return (unsigned short)(v.i >> 16);
}
__device__ __forceinline__ short8 ld8(const unsigned short* p) {
    return *reinterpret_cast<const short8*>(p);
}
__device__ __forceinline__ void st8(unsigned short* p, short8 v) {
    *reinterpret_cast<short8*>(p) = v;
}
__device__ __forceinline__ f32x4 mfma16(short8 a, short8 b, f32x4 c) {
    return __builtin_amdgcn_mfma_f32_16x16x32_bf16(a, b, c, 0, 0, 0);
}
__device__ __forceinline__ void stC(float* p, float v)          { *p = v; }
__device__ __forceinline__ void stC(unsigned short* p, float v) { *p = f2b(v); }

// ---------------------------------------------------------------------------
// Stage 0: x (fp32) -> xbf (bf16).  4M elements, 4/thread.
// ---------------------------------------------------------------------------
__global__ __launch_bounds__(256) void cvt_kernel(const float* __restrict__ in,
                                                  unsigned short* __restrict__ out)
{
    int i = blockIdx.x * 256 + threadIdx.x;
    float4v v = reinterpret_cast<const float4v*>(in)[i];
    u16x4 o;
#pragma unroll
    for (int j = 0; j < 4; ++j) o[j] = f2b(v[j]);
    reinterpret_cast<u16x4*>(out)[i] = o;
}

// ---------------------------------------------------------------------------
// Stage 1: style[map][b][i] = dot(s[b,:], aff_w[i,:]) + aff_b[i]   (fp32)
// ---------------------------------------------------------------------------
__global__ __launch_bounds__(256) void style_kernel(
    const float* __restrict__ s,
    const float* __restrict__ k_aff_w, const float* __restrict__ k_aff_b,
    const float* __restrict__ o_aff_w, const float* __restrict__ o_aff_b,
    float* __restrict__ style)
{
    int wid  = blockIdx.x * 4 + (threadIdx.x >> 6);
    int lane = threadIdx.x & 63;
    int map  = wid >> 12;
    int rem  = wid & 4095;
    int b    = rem >> 9;
    int i    = rem & 511;
    const float* aw = map ? o_aff_w : k_aff_w;
    const float* ab = map ? o_aff_b : k_aff_b;
    const float* sp = s  + b * 512 + lane * 8;
    const float* wp = aw + i * 512 + lane * 8;
    float acc = 0.f;
#pragma unroll
    for (int j = 0; j < 8; ++j) acc += sp[j] * wp[j];
#pragma unroll
    for (int off = 1; off < 64; off <<= 1) acc += __shfl_xor(acc, off, 64);
    if (lane == 0) style[(map * 8 + b) * 512 + i] = acc + ab[i];
}

// ---------------------------------------------------------------------------
// Stage 2: wmod[map][b][o][i] = bf16( weight[o][i]*style[map][b][i] * demod )
// ---------------------------------------------------------------------------
__global__ __launch_bounds__(256) void modw_kernel(
    const float* __restrict__ k_weight,
    const float* __restrict__ o_weight,
    const float* __restrict__ style,
    unsigned short* __restrict__ wmod)
{
    int wid  = blockIdx.x * 4 + (threadIdx.x >> 6);
    int lane = threadIdx.x & 63;
    int map  = wid >> 12;
    int rem  = wid & 4095;
    int b    = rem >> 9;
    int o    = rem & 511;
    const float* wrow = (map ? o_weight : k_weight) + o * 512 + lane * 8;
    const float* st   = style + (map * 8 + b) * 512 + lane * 8;
    float w[8]; float ss = 0.f;
#pragma unroll
    for (int j = 0; j < 8; ++j) { w[j] = wrow[j] * st[j]; ss += w[j] * w[j]; }
#pragma unroll
    for (int off = 1; off < 64; off <<= 1) ss += __shfl_xor(ss, off, 64);
    float demod = rsqrtf(ss + 1e-8f);
    short8 ov;
#pragma unroll
    for (int j = 0; j < 8; ++j) ov[j] = (short)f2b(w[j] * demod);
    unsigned short* dst = wmod + (((size_t)map * 8 + b) * 512 + o) * 512 + lane * 8;
    *reinterpret_cast<short8*>(dst) = ov;
}

// ---------------------------------------------------------------------------
// Stage 3/5 (R10): batched GEMM — FULL-K LDS, zero K-loop barriers.
// C[b][m][n] = sum_k A[b][m][k] * Bt[b][n][k];  M=1024, N=512, K=512, B=8.
// The whole 64-row A-tile and 64-row B-tile (128 KB) are staged ONCE
// (single barrier), then 16 K-steps run as pure ds_read+MFMA with constant
// immediate offsets — no barriers, no global loads, no address VALU in the
// hot loop. This removes the per-iteration barrier/waitcnt drain that R5/
// R8/R9 all shared (each halving of barrier count gave a measurable gain).
// KP=520: rows 1040 B (16B-aligned, R7 lesson); dword stride 260 === 4
// (mod 32) -> only free 2-way read aliasing (R9 math). LDS 130 KB dynamic
// (hipFuncSetAttribute) -> 1 block/CU, grid 1024 = 4 generations.
// b = blk&7: batch-per-XCD L2 locality (R9).
// WVT: fused epilogue writes VT[b*8+nt][d][token] via in-LDS transpose.
// ---------------------------------------------------------------------------
template <typename CT, bool WVT>
__global__ __launch_bounds__(256) void gemm_fullk_kernel(
    const unsigned short* __restrict__ A,
    const unsigned short* __restrict__ Bt,
    CT* __restrict__ C,
    unsigned short* __restrict__ VT)
{
    constexpr int KP = 520;
    constexpr int TP = 72;    // Tt row: 144 B (16B multiple)
    extern __shared__ __align__(16) unsigned short smem[];
    unsigned short (*As)[KP] = reinterpret_cast<unsigned short (*)[KP]>(smem);
    unsigned short (*Bs)[KP] = reinterpret_cast<unsigned short (*)[KP]>(smem + 64 * KP);

    int blk = blockIdx.x;
    int b   = blk & 7;            // XCD = batch
    int rem = blk >> 3;
    int mt  = rem & 15;
    int nt  = rem >> 4;           // 0..7
    int tid  = threadIdx.x;
    int w    = tid >> 6;
    int lane = tid & 63;
    int quad = lane >> 4;
    int r    = lane & 15;
    int wm   = w >> 1;            // 0..1 (M half)
    int wn   = w & 1;             // 0..1 (N half)

    const unsigned short* Ab = A  + ((size_t)b * 1024 + mt * 64) * 512;
    const unsigned short* Bb = Bt + ((size_t)b * 512  + nt * 64) * 512;

    // staging: thread t owns row t>>2 (0..63); 16 chunks of 16 B at
    // elem col (t&3)*8 + j*32 (4 consecutive threads cover 64 B) for A and B.
    int srow = tid >> 2;
    int sc0  = (tid & 3) * 8;
    const unsigned short* ga = Ab + (size_t)srow * 512 + sc0;
    const unsigned short* gb = Bb + (size_t)srow * 512 + sc0;
    unsigned short* la = &As[srow][sc0];
    unsigned short* lb = &Bs[srow][sc0];
#pragma unroll
    for (int half = 0; half < 2; ++half) {
        short8 t[8];
#pragma unroll
        for (int j = 0; j < 8; ++j) t[j] = ld8(ga + (half * 8 + j) * 32);
#pragma unroll
        for (int j = 0; j < 8; ++j) st8(la + (half * 8 + j) * 32, t[j]);
#pragma unroll
        for (int j = 0; j < 8; ++j) t[j] = ld8(gb + (half * 8 + j) * 32);
#pragma unroll
        for (int j = 0; j < 8; ++j) st8(lb + (half * 8 + j) * 32, t[j]);
    }
    __syncthreads();              // the ONLY pre-epilogue barrier

    f32x4 acc[2][2];
#pragma unroll
    for (int i = 0; i < 2; ++i)
#pragma unroll
        for (int j = 0; j < 2; ++j) acc[i][j] = f32x4{0.f, 0.f, 0.f, 0.f};

    const unsigned short* a0 = &As[wm * 32 + r][quad * 8];
    const unsigned short* a1 = &As[wm * 32 + 16 + r][quad * 8];
    const unsigned short* b0 = &Bs[wn * 32 + r][quad * 8];
    const unsigned short* b1 = &Bs[wn * 32 + 16 + r][quad * 8];
#pragma unroll
    for (int ks = 0; ks < 16; ++ks) {
        short8 af0 = ld8(a0 + ks * 32);
        short8 af1 = ld8(a1 + ks * 32);
        short8 bf0 = ld8(b0 + ks * 32);
        short8 bf1 = ld8(b1 + ks * 32);
        acc[0][0] = mfma16(af0, bf0, acc[0][0]);
        acc[0][1] = mfma16(af0, bf1, acc[0][1]);
        acc[1][0] = mfma16(af1, bf0, acc[1][0]);
        acc[1][1] = mfma16(af1, bf1, acc[1][1]);
    }

    CT* Cb = C + (size_t)b * 1024 * 512;
#pragma unroll
    for (int i = 0; i < 2; ++i)
#pragma unroll
        for (int rr = 0; rr < 4; ++rr) {
            int row = mt * 64 + wm * 32 + i * 16 + quad * 4 + rr;
#pragma unroll
            for (int j = 0; j < 2; ++j) {
                int col = nt * 64 + wn * 32 + j * 16 + r;
                stC(Cb + (size_t)row * 512 + col, acc[i][j][rr]);
            }
        }
    if (WVT) {
        __syncthreads();          // all waves done reading As/Bs
        unsigned short (*Tt)[TP] = reinterpret_cast<unsigned short (*)[TP]>(smem);
#pragma unroll
        for (int i = 0; i < 2; ++i)
#pragma unroll
            for (int j = 0; j < 2; ++j) {
                int d = wn * 32 + j * 16 + r;
#pragma unroll
                for (int rh = 0; rh < 2; ++rh) {
                    int tok = wm * 32 + i * 16 + quad * 4 + rh * 2;
                    unsigned int pv = (unsigned int)f2b(acc[i][j][rh * 2]) |
                                      ((unsigned int)f2b(acc[i][j][rh * 2 + 1]) << 16);
                    *reinterpret_cast<unsigned int*>(&Tt[d][tok]) = pv;
                }
            }
        __syncthreads();
        int d  = tid >> 2;          // 0..63
        int cc = tid & 3;           // token chunk of 16
        const unsigned short* src = &Tt[d][cc * 16];
        unsigned short* dst = VT + ((size_t)(b * 8 + nt) * 64 + d) * 1024 + mt * 64 + cc * 16;
        short8 t0 = ld8(src), t1 = ld8(src + 8);
        st8(dst,     t0);
        st8(dst + 8, t1);
    }
}

// ---------------------------------------------------------------------------
// Stage 4: flash attention — frozen at best measured config (49.4 us, R5/R8).
// PAD=72 (16B-aligned rows), 16 q-rows/wave, grid 1024, static-max softmax,
// cooperative K/V staging + VGPR prefetch, wave-private P round-trip.
// ---------------------------------------------------------------------------
__global__ __launch_bounds__(256) void attn_kernel(
    const unsigned short* __restrict__ kqv,
    const unsigned short* __restrict__ vt,
    unsigned short* __restrict__ attn_out)
{
    constexpr int PAD = 72;
    int blk = blockIdx.x;
    int bh = blk & 63;            // XCD-locality: same bh every 64 blocks
    int qt = blk >> 6;            // 0..15
    int b  = bh >> 3, h = bh & 7;
    int tid  = threadIdx.x;
    int wv   = tid >> 6;
    int lane = tid & 63;
    int quad = lane >> 4;
    int r    = lane & 15;

    __shared__ __align__(16) unsigned short klds[2][64][PAD];
    __shared__ __align__(16) unsigned short vlds[2][64][PAD];
    __shared__ __align__(16) unsigned short plds[4][16][PAD];
    unsigned short* myp = &plds[wv][0][0];

    const unsigned short* Mb = kqv + (size_t)b * 1024 * 512;
    int q0 = qt * 64 + wv * 16;

    const unsigned short* qptr = Mb + (size_t)(q0 + r) * 512 + h * 64 + quad * 8;
    short8 bq0 = ld8(qptr);
    short8 bq1 = ld8(qptr + 32);

    short8 ones;
#pragma unroll
    for (int j = 0; j < 8; ++j) ones[j] = (short)0x3F80;   // bf16 1.0

    f32x4 o0 = {0.f, 0.f, 0.f, 0.f};
    f32x4 o1 = o0, o2 = o0, o3 = o0, lacc = o0;

    int srow0 = tid >> 3;
    int srow1 = srow0 + 32;
    int scol  = (tid & 7) * 8;
    const unsigned short* Kg = Mb + h * 64;
    const unsigned short* Vg = vt + (size_t)bh * 64 * 1024;

    {
        short8 k0v = ld8(Kg + (size_t)srow0 * 512 + scol);
        short8 k1v = ld8(Kg + (size_t)srow1 * 512 + scol);
        short8 v0v = ld8(Vg + (size_t)srow0 * 1024 + scol);
        short8 v1v = ld8(Vg + (size_t)srow1 * 1024 + scol);
        st8(&klds[0][srow0][scol], k0v);
        st8(&klds[0][srow1][scol], k1v);
        st8(&vlds[0][srow0][scol], v0v);
        st8(&vlds[0][srow1][scol], v1v);
    }
    __syncthreads();

    const float c  = 0.18033688011112042f;   // (1/8) * log2(e)
    const float CM = 28.853900817779268f;    // 20 * log2(e)

    for (int it = 0; it < 16; ++it) {
        int s = it & 1;
        short8 pk0, pk1, pv0, pv1;
        if (it < 15) {
            int k0n = (it + 1) * 64;
            pk0 = ld8(Kg + (size_t)(k0n + srow0) * 512 + scol);
            pk1 = ld8(Kg + (size_t)(k0n + srow1) * 512 + scol);
            pv0 = ld8(Vg + (size_t)srow0 * 1024 + k0n + scol);
            pv1 = ld8(Vg + (size_t)srow1 * 1024 + k0n + scol);
        }
        // ---- S^T: lane holds 16 scores for q-col r
        f32x4 st_[4];
#pragma unroll
        for (int t = 0; t < 4; ++t) {
            short8 ka = ld8(&klds[s][t * 16 + r][quad * 8]);
            short8 kb = ld8(&klds[s][t * 16 + r][32 + quad * 8]);
            f32x4 sacc = {0.f, 0.f, 0.f, 0.f};
            sacc = mfma16(ka, bq0, sacc);
            sacc = mfma16(kb, bq1, sacc);
            st_[t] = sacc;
        }
        // ---- P = exp2(s*c - CM), truncate-to-bf16, wave-private LDS
#pragma unroll
        for (int t = 0; t < 4; ++t) {
            u16x4 pb;
#pragma unroll
            for (int rr = 0; rr < 4; ++rr)
                pb[rr] = f2bt(exp2f(st_[t][rr] * c - CM));
            *reinterpret_cast<u16x4*>(&myp[r * PAD + t * 16 + quad * 4]) = pb;
        }
        // ---- PV + l from staged V tile
        short8 ap0 = ld8(&myp[r * PAD + quad * 8]);
        short8 ap1 = ld8(&myp[r * PAD + 32 + quad * 8]);
        {
            short8 va, vb;
            va = ld8(&vlds[s][0 * 16 + r][quad * 8]);
            vb = ld8(&vlds[s][0 * 16 + r][32 + quad * 8]);
            o0 = mfma16(ap0, va, o0);  o0 = mfma16(ap1, vb, o0);
            va = ld8(&vlds[s][1 * 16 + r][quad * 8]);
            vb = ld8(&vlds[s][1 * 16 + r][32 + quad * 8]);
            o1 = mfma16(ap0, va, o1);  o1 = mfma16(ap1, vb, o1);
            va = ld8(&vlds[s][2 * 16 + r][quad * 8]);
            vb = ld8(&vlds[s][2 * 16 + r][32 + quad * 8]);
            o2 = mfma16(ap0, va, o2);  o2 = mfma16(ap1, vb, o2);
            va = ld8(&vlds[s][3 * 16 + r][quad * 8]);
            vb = ld8(&vlds[s][3 * 16 + r][32 + quad * 8]);
            o3 = mfma16(ap0, va, o3);  o3 = mfma16(ap1, vb, o3);
            lacc = mfma16(ap0, ones, lacc);
            lacc = mfma16(ap1, ones, lacc);
        }
        if (it < 15) {
            int ns = s ^ 1;
            st8(&klds[ns][srow0][scol], pk0);
            st8(&klds[ns][srow1][scol], pk1);
            st8(&vlds[ns][srow0][scol], pv0);
            st8(&vlds[ns][srow1][scol], pv1);
        }
        __syncthreads();
    }

    unsigned short* ob = attn_out + (size_t)b * 1024 * 512 + (size_t)h * 64;
#pragma unroll
    for (int rr = 0; rr < 4; ++rr) {
        float inv = 1.0f / lacc[rr];
        int n = q0 + quad * 4 + rr;
        unsigned short* orow = ob + (size_t)n * 512 + r;
        orow[0]  = f2b(o0[rr] * inv);
        orow[16] = f2b(o1[rr] * inv);
        orow[32] = f2b(o2[rr] * inv);
        orow[48] = f2b(o3[rr] * inv);
    }
}

// ---------------------------------------------------------------------------
extern "C" void kernel_launch(void* const* d_in, const int* in_sizes, int n_in,
                              void* d_out, int out_size, void* d_ws, size_t ws_size,
                              hipStream_t stream)
{
    const float* x        = (const float*)d_in[0];
    const float* s        = (const float*)d_in[1];
    const float* k_weight = (const float*)d_in[2];
    const float* k_aff_w  = (const float*)d_in[3];
    const float* k_aff_b  = (const float*)d_in[4];
    const float* o_weight = (const float*)d_in[5];
    const float* o_aff_w  = (const float*)d_in[6];
    const float* o_aff_b  = (const float*)d_in[7];
    float* out = (float*)d_out;

    char* ws = (char*)d_ws;
    float* style          = (float*)ws;                                   // 32 KB
    unsigned short* wmod  = (unsigned short*)(ws + 32 * 1024);            // 8 MB (both maps)
    unsigned short* xbf   = wmod + (size_t)2 * 8 * 512 * 512;             // 8 MB (reused as attn)
    unsigned short* kqv   = xbf  + (size_t)8 * 1024 * 512;                // 8 MB
    unsigned short* vt    = kqv  + (size_t)8 * 1024 * 512;                // 8 MB
    unsigned short* attn  = xbf;   // x is dead after GEMM1 -> alias

    constexpr int GEMM_LDS = 2 * 64 * 520 * 2;   // 133,120 B dynamic
    // idempotent; first (non-captured) correctness call sets it persistently
    (void)hipFuncSetAttribute((const void*)gemm_fullk_kernel<unsigned short, true>,
                              hipFuncAttributeMaxDynamicSharedMemorySize, GEMM_LDS);
    (void)hipFuncSetAttribute((const void*)gemm_fullk_kernel<float, false>,
                              hipFuncAttributeMaxDynamicSharedMemorySize, GEMM_LDS);

    cvt_kernel<<<4096, 256, 0, stream>>>(x, xbf);
    style_kernel<<<2048, 256, 0, stream>>>(s, k_aff_w, k_aff_b, o_aff_w, o_aff_b, style);
    modw_kernel<<<2048, 256, 0, stream>>>(k_weight, o_weight, style, wmod);
    gemm_fullk_kernel<unsigned short, true><<<1024, 256, GEMM_LDS, stream>>>(xbf, wmod, kqv, vt);
    attn_kernel<<<1024, 256, 0, stream>>>(kqv, vt, attn);
    gemm_fullk_kernel<float, false><<<1024, 256, GEMM_LDS, stream>>>(attn, wmod + (size_t)8 * 512 * 512, out, nullptr);
}

// Round 11
// 152.457 us; speedup vs baseline: 1.0558x; 1.0558x over previous
//
#include <hip/hip_runtime.h>
#include <stdint.h>

using short8  = __attribute__((ext_vector_type(8))) short;   // 8 bf16 = 4 VGPRs
using f32x4   = __attribute__((ext_vector_type(4))) float;
using float4v = __attribute__((ext_vector_type(4))) float;
using u16x4   = __attribute__((ext_vector_type(4))) unsigned short;

__device__ __forceinline__ unsigned short f2b(float f) {
    union { float f; unsigned int i; } v; v.f = f;
    unsigned int i = v.i;
    unsigned int r = (i + 0x7fffu + ((i >> 16) & 1u)) >> 16;   // RNE
    return (unsigned short)r;
}
__device__ __forceinline__ unsigned short f2bt(float f) {      // truncate (1 VALU)
    union { float f; unsigned int i; } v; v.f = f;
    return (unsigned short)(v.i >> 16);
}
__device__ __forceinline__ short8 ld8(const unsigned short* p) {
    return *reinterpret_cast<const short8*>(p);
}
__device__ __forceinline__ void st8(unsigned short* p, short8 v) {
    *reinterpret_cast<short8*>(p) = v;
}
// A-operand load: 8 elements -> bf16x8 (identity for bf16, convert for fp32)
__device__ __forceinline__ short8 ldA(const unsigned short* p) { return ld8(p); }
__device__ __forceinline__ short8 ldA(const float* p) {
    float4v v0 = *reinterpret_cast<const float4v*>(p);
    float4v v1 = *reinterpret_cast<const float4v*>(p + 4);
    short8 o;
#pragma unroll
    for (int j = 0; j < 4; ++j) o[j] = (short)f2b(v0[j]);
#pragma unroll
    for (int j = 0; j < 4; ++j) o[4 + j] = (short)f2b(v1[j]);
    return o;
}
__device__ __forceinline__ f32x4 mfma16(short8 a, short8 b, f32x4 c) {
    return __builtin_amdgcn_mfma_f32_16x16x32_bf16(a, b, c, 0, 0, 0);
}
__device__ __forceinline__ void stC(float* p, float v)          { *p = v; }
__device__ __forceinline__ void stC(unsigned short* p, float v) { *p = f2b(v); }

// ---------------------------------------------------------------------------
// Stage 1: style[map][b][i] = dot(s[b,:], aff_w[i,:]) + aff_b[i]   (fp32)
// ---------------------------------------------------------------------------
__global__ __launch_bounds__(256) void style_kernel(
    const float* __restrict__ s,
    const float* __restrict__ k_aff_w, const float* __restrict__ k_aff_b,
    const float* __restrict__ o_aff_w, const float* __restrict__ o_aff_b,
    float* __restrict__ style)
{
    int wid  = blockIdx.x * 4 + (threadIdx.x >> 6);
    int lane = threadIdx.x & 63;
    int map  = wid >> 12;
    int rem  = wid & 4095;
    int b    = rem >> 9;
    int i    = rem & 511;
    const float* aw = map ? o_aff_w : k_aff_w;
    const float* ab = map ? o_aff_b : k_aff_b;
    const float* sp = s  + b * 512 + lane * 8;
    const float* wp = aw + i * 512 + lane * 8;
    float acc = 0.f;
#pragma unroll
    for (int j = 0; j < 8; ++j) acc += sp[j] * wp[j];
#pragma unroll
    for (int off = 1; off < 64; off <<= 1) acc += __shfl_xor(acc, off, 64);
    if (lane == 0) style[(map * 8 + b) * 512 + i] = acc + ab[i];
}

// ---------------------------------------------------------------------------
// Stage 2: wmod[map][b][o][i] = bf16( weight[o][i]*style[map][b][i] * demod )
// ---------------------------------------------------------------------------
__global__ __launch_bounds__(256) void modw_kernel(
    const float* __restrict__ k_weight,
    const float* __restrict__ o_weight,
    const float* __restrict__ style,
    unsigned short* __restrict__ wmod)
{
    int wid  = blockIdx.x * 4 + (threadIdx.x >> 6);
    int lane = threadIdx.x & 63;
    int map  = wid >> 12;
    int rem  = wid & 4095;
    int b    = rem >> 9;
    int o    = rem & 511;
    const float* wrow = (map ? o_weight : k_weight) + o * 512 + lane * 8;
    const float* st   = style + (map * 8 + b) * 512 + lane * 8;
    float w[8]; float ss = 0.f;
#pragma unroll
    for (int j = 0; j < 8; ++j) { w[j] = wrow[j] * st[j]; ss += w[j] * w[j]; }
#pragma unroll
    for (int off = 1; off < 64; off <<= 1) ss += __shfl_xor(ss, off, 64);
    float demod = rsqrtf(ss + 1e-8f);
    short8 ov;
#pragma unroll
    for (int j = 0; j < 8; ++j) ov[j] = (short)f2b(w[j] * demod);
    unsigned short* dst = wmod + (((size_t)map * 8 + b) * 512 + o) * 512 + lane * 8;
    *reinterpret_cast<short8*>(dst) = ov;
}

// ---------------------------------------------------------------------------
// Stage 3/5 (R11): batched GEMM — R9 structure (best measured) + fused cvt.
// C[b][m][n] = sum_k A[b][m][k] * Bt[b][n][k];  M=1024, N=512, K=512, B=8.
// AT=float (GEMM1): reads fp32 x directly, converts to bf16 during staging
// (deletes the cvt dispatch + 24 MB round-trip). AT=ushort (GEMM2): as R9.
//  - b = blk&7: batch-per-XCD L2 locality (R9-measured win)
//  - BK=64, depth-2 prefetch: ds_write commit consumes registers loaded one
//    full iteration earlier -> vmcnt waits hit completed loads
// Tile 64x64, 4 waves (2x2), wave tile 32x32. KP=72 (144B rows, 16B-aligned
// — R7 lesson; 2-way frag-read aliasing only). LDS 36 KB, grid 1024.
// WVT: fused epilogue writes VT[b*8+nt][d][token] via in-LDS transpose.
// ---------------------------------------------------------------------------
template <typename AT, typename CT, bool WVT>
__global__ __launch_bounds__(256) void gemm_bt_lds_kernel(
    const AT* __restrict__ A,
    const unsigned short* __restrict__ Bt,
    CT* __restrict__ C,
    unsigned short* __restrict__ VT)
{
    constexpr int KP = 72;
    constexpr int TP = 72;    // Tt row: 144 B (16B multiple)
    __shared__ __align__(16) unsigned short smem[4 * 64 * KP];   // 36 KB
    typedef unsigned short Plane[64][KP];
    Plane* As = reinterpret_cast<Plane*>(smem);                  // [2][64][KP]
    Plane* Bs = reinterpret_cast<Plane*>(smem + 2 * 64 * KP);    // [2][64][KP]

    int blk = blockIdx.x;
    int b   = blk & 7;            // XCD = batch
    int rem = blk >> 3;
    int mt  = rem & 15;
    int nt  = rem >> 4;           // 0..7
    int tid  = threadIdx.x;
    int w    = tid >> 6;
    int lane = tid & 63;
    int quad = lane >> 4;
    int r    = lane & 15;
    int wm   = w >> 1;            // 0..1 (M half)
    int wn   = w & 1;             // 0..1 (N half)

    const AT*             Ab = A  + ((size_t)b * 1024 + mt * 64) * 512;
    const unsigned short* Bb = Bt + ((size_t)b * 512  + nt * 64) * 512;

    // staging: thread t covers row t>>2 (0..63), element chunks (t&3)*8 and +32
    int srow = tid >> 2;
    int scol = (tid & 3) * 8;
    const AT*             ga = Ab + (size_t)srow * 512 + scol;
    const unsigned short* gb = Bb + (size_t)srow * 512 + scol;

    f32x4 acc[2][2];
#pragma unroll
    for (int i = 0; i < 2; ++i)
#pragma unroll
        for (int j = 0; j < 2; ++j) acc[i][j] = f32x4{0.f, 0.f, 0.f, 0.f};

    short8 rg[2][4];   // [tile parity][a-lo, a-hi, b-lo, b-hi]

    // prologue: tile 0 direct to LDS buf 0; tile 1 into rg[1]
    st8(&As[0][srow][scol],      ldA(ga));
    st8(&As[0][srow][scol + 32], ldA(ga + 32));
    st8(&Bs[0][srow][scol],      ld8(gb));
    st8(&Bs[0][srow][scol + 32], ld8(gb + 32));
    rg[1][0] = ldA(ga + 64);  rg[1][1] = ldA(ga + 96);
    rg[1][2] = ld8(gb + 64);  rg[1][3] = ld8(gb + 96);
    __syncthreads();

#pragma unroll
    for (int ks = 0; ks < 8; ++ks) {
        int s = ks & 1;
        if (ks < 6) {                         // load tile ks+2 (consumed next iter)
            int ko = (ks + 2) * 64;
            rg[s][0] = ldA(ga + ko);       rg[s][1] = ldA(ga + ko + 32);
            rg[s][2] = ld8(gb + ko);       rg[s][3] = ld8(gb + ko + 32);
        }
#pragma unroll
        for (int kh = 0; kh < 2; ++kh) {
            short8 af[2], bf[2];
#pragma unroll
            for (int i = 0; i < 2; ++i)
                af[i] = ld8(&As[s][wm * 32 + i * 16 + r][kh * 32 + quad * 8]);
#pragma unroll
            for (int j = 0; j < 2; ++j)
                bf[j] = ld8(&Bs[s][wn * 32 + j * 16 + r][kh * 32 + quad * 8]);
#pragma unroll
            for (int i = 0; i < 2; ++i)
#pragma unroll
                for (int j = 0; j < 2; ++j)
                    acc[i][j] = mfma16(af[i], bf[j], acc[i][j]);
        }
        if (ks < 7) {                         // commit tile ks+1 (loaded last iter)
            int ns = s ^ 1;
            st8(&As[ns][srow][scol],      rg[ns][0]);
            st8(&As[ns][srow][scol + 32], rg[ns][1]);
            st8(&Bs[ns][srow][scol],      rg[ns][2]);
            st8(&Bs[ns][srow][scol + 32], rg[ns][3]);
        }
        __syncthreads();
    }

    CT* Cb = C + (size_t)b * 1024 * 512;
#pragma unroll
    for (int i = 0; i < 2; ++i)
#pragma unroll
        for (int rr = 0; rr < 4; ++rr) {
            int row = mt * 64 + wm * 32 + i * 16 + quad * 4 + rr;
#pragma unroll
            for (int j = 0; j < 2; ++j) {
                int col = nt * 64 + wn * 32 + j * 16 + r;
                stC(Cb + (size_t)row * 512 + col, acc[i][j][rr]);
            }
        }
    if (WVT) {
        // last K-iteration ended at a barrier: smem reusable
        unsigned short (*Tt)[TP] = reinterpret_cast<unsigned short (*)[TP]>(smem);
#pragma unroll
        for (int i = 0; i < 2; ++i)
#pragma unroll
            for (int j = 0; j < 2; ++j) {
                int d = wn * 32 + j * 16 + r;
#pragma unroll
                for (int rh = 0; rh < 2; ++rh) {
                    int tok = wm * 32 + i * 16 + quad * 4 + rh * 2;
                    unsigned int pv = (unsigned int)f2b(acc[i][j][rh * 2]) |
                                      ((unsigned int)f2b(acc[i][j][rh * 2 + 1]) << 16);
                    *reinterpret_cast<unsigned int*>(&Tt[d][tok]) = pv;
                }
            }
        __syncthreads();
        int d  = tid >> 2;          // 0..63
        int cc = tid & 3;           // token chunk of 16
        const unsigned short* src = &Tt[d][cc * 16];
        unsigned short* dst = VT + ((size_t)(b * 8 + nt) * 64 + d) * 1024 + mt * 64 + cc * 16;
        short8 t0 = ld8(src), t1 = ld8(src + 8);
        st8(dst,     t0);
        st8(dst + 8, t1);
    }
}

// ---------------------------------------------------------------------------
// Stage 4: flash attention — frozen at best measured config (49.4 us, R5/R8).
// PAD=72 (16B-aligned rows), 16 q-rows/wave, grid 1024, static-max softmax,
// cooperative K/V staging + VGPR prefetch, wave-private P round-trip.
// ---------------------------------------------------------------------------
__global__ __launch_bounds__(256) void attn_kernel(
    const unsigned short* __restrict__ kqv,
    const unsigned short* __restrict__ vt,
    unsigned short* __restrict__ attn_out)
{
    constexpr int PAD = 72;
    int blk = blockIdx.x;
    int bh = blk & 63;            // XCD-locality: same bh every 64 blocks
    int qt = blk >> 6;            // 0..15
    int b  = bh >> 3, h = bh & 7;
    int tid  = threadIdx.x;
    int wv   = tid >> 6;
    int lane = tid & 63;
    int quad = lane >> 4;
    int r    = lane & 15;

    __shared__ __align__(16) unsigned short klds[2][64][PAD];
    __shared__ __align__(16) unsigned short vlds[2][64][PAD];
    __shared__ __align__(16) unsigned short plds[4][16][PAD];
    unsigned short* myp = &plds[wv][0][0];

    const unsigned short* Mb = kqv + (size_t)b * 1024 * 512;
    int q0 = qt * 64 + wv * 16;

    const unsigned short* qptr = Mb + (size_t)(q0 + r) * 512 + h * 64 + quad * 8;
    short8 bq0 = ld8(qptr);
    short8 bq1 = ld8(qptr + 32);

    short8 ones;
#pragma unroll
    for (int j = 0; j < 8; ++j) ones[j] = (short)0x3F80;   // bf16 1.0

    f32x4 o0 = {0.f, 0.f, 0.f, 0.f};
    f32x4 o1 = o0, o2 = o0, o3 = o0, lacc = o0;

    int srow0 = tid >> 3;
    int srow1 = srow0 + 32;
    int scol  = (tid & 7) * 8;
    const unsigned short* Kg = Mb + h * 64;
    const unsigned short* Vg = vt + (size_t)bh * 64 * 1024;

    {
        short8 k0v = ld8(Kg + (size_t)srow0 * 512 + scol);
        short8 k1v = ld8(Kg + (size_t)srow1 * 512 + scol);
        short8 v0v = ld8(Vg + (size_t)srow0 * 1024 + scol);
        short8 v1v = ld8(Vg + (size_t)srow1 * 1024 + scol);
        st8(&klds[0][srow0][scol], k0v);
        st8(&klds[0][srow1][scol], k1v);
        st8(&vlds[0][srow0][scol], v0v);
        st8(&vlds[0][srow1][scol], v1v);
    }
    __syncthreads();

    const float c  = 0.18033688011112042f;   // (1/8) * log2(e)
    const float CM = 28.853900817779268f;    // 20 * log2(e)

    for (int it = 0; it < 16; ++it) {
        int s = it & 1;
        short8 pk0, pk1, pv0, pv1;
        if (it < 15) {
            int k0n = (it + 1) * 64;
            pk0 = ld8(Kg + (size_t)(k0n + srow0) * 512 + scol);
            pk1 = ld8(Kg + (size_t)(k0n + srow1) * 512 + scol);
            pv0 = ld8(Vg + (size_t)srow0 * 1024 + k0n + scol);
            pv1 = ld8(Vg + (size_t)srow1 * 1024 + k0n + scol);
        }
        // ---- S^T: lane holds 16 scores for q-col r
        f32x4 st_[4];
#pragma unroll
        for (int t = 0; t < 4; ++t) {
            short8 ka = ld8(&klds[s][t * 16 + r][quad * 8]);
            short8 kb = ld8(&klds[s][t * 16 + r][32 + quad * 8]);
            f32x4 sacc = {0.f, 0.f, 0.f, 0.f};
            sacc = mfma16(ka, bq0, sacc);
            sacc = mfma16(kb, bq1, sacc);
            st_[t] = sacc;
        }
        // ---- P = exp2(s*c - CM), truncate-to-bf16, wave-private LDS
#pragma unroll
        for (int t = 0; t < 4; ++t) {
            u16x4 pb;
#pragma unroll
            for (int rr = 0; rr < 4; ++rr)
                pb[rr] = f2bt(exp2f(st_[t][rr] * c - CM));
            *reinterpret_cast<u16x4*>(&myp[r * PAD + t * 16 + quad * 4]) = pb;
        }
        // ---- PV + l from staged V tile
        short8 ap0 = ld8(&myp[r * PAD + quad * 8]);
        short8 ap1 = ld8(&myp[r * PAD + 32 + quad * 8]);
        {
            short8 va, vb;
            va = ld8(&vlds[s][0 * 16 + r][quad * 8]);
            vb = ld8(&vlds[s][0 * 16 + r][32 + quad * 8]);
            o0 = mfma16(ap0, va, o0);  o0 = mfma16(ap1, vb, o0);
            va = ld8(&vlds[s][1 * 16 + r][quad * 8]);
            vb = ld8(&vlds[s][1 * 16 + r][32 + quad * 8]);
            o1 = mfma16(ap0, va, o1);  o1 = mfma16(ap1, vb, o1);
            va = ld8(&vlds[s][2 * 16 + r][quad * 8]);
            vb = ld8(&vlds[s][2 * 16 + r][32 + quad * 8]);
            o2 = mfma16(ap0, va, o2);  o2 = mfma16(ap1, vb, o2);
            va = ld8(&vlds[s][3 * 16 + r][quad * 8]);
            vb = ld8(&vlds[s][3 * 16 + r][32 + quad * 8]);
            o3 = mfma16(ap0, va, o3);  o3 = mfma16(ap1, vb, o3);
            lacc = mfma16(ap0, ones, lacc);
            lacc = mfma16(ap1, ones, lacc);
        }
        if (it < 15) {
            int ns = s ^ 1;
            st8(&klds[ns][srow0][scol], pk0);
            st8(&klds[ns][srow1][scol], pk1);
            st8(&vlds[ns][srow0][scol], pv0);
            st8(&vlds[ns][srow1][scol], pv1);
        }
        __syncthreads();
    }

    unsigned short* ob = attn_out + (size_t)b * 1024 * 512 + (size_t)h * 64;
#pragma unroll
    for (int rr = 0; rr < 4; ++rr) {
        float inv = 1.0f / lacc[rr];
        int n = q0 + quad * 4 + rr;
        unsigned short* orow = ob + (size_t)n * 512 + r;
        orow[0]  = f2b(o0[rr] * inv);
        orow[16] = f2b(o1[rr] * inv);
        orow[32] = f2b(o2[rr] * inv);
        orow[48] = f2b(o3[rr] * inv);
    }
}

// ---------------------------------------------------------------------------
extern "C" void kernel_launch(void* const* d_in, const int* in_sizes, int n_in,
                              void* d_out, int out_size, void* d_ws, size_t ws_size,
                              hipStream_t stream)
{
    const float* x        = (const float*)d_in[0];
    const float* s        = (const float*)d_in[1];
    const float* k_weight = (const float*)d_in[2];
    const float* k_aff_w  = (const float*)d_in[3];
    const float* k_aff_b  = (const float*)d_in[4];
    const float* o_weight = (const float*)d_in[5];
    const float* o_aff_w  = (const float*)d_in[6];
    const float* o_aff_b  = (const float*)d_in[7];
    float* out = (float*)d_out;

    char* ws = (char*)d_ws;
    float* style          = (float*)ws;                                   // 32 KB
    unsigned short* wmod  = (unsigned short*)(ws + 32 * 1024);            // 8 MB (both maps)
    unsigned short* attn  = wmod + (size_t)2 * 8 * 512 * 512;             // 8 MB
    unsigned short* kqv   = attn + (size_t)8 * 1024 * 512;                // 8 MB
    unsigned short* vt    = kqv  + (size_t)8 * 1024 * 512;                // 8 MB

    style_kernel<<<2048, 256, 0, stream>>>(s, k_aff_w, k_aff_b, o_aff_w, o_aff_b, style);
    modw_kernel<<<2048, 256, 0, stream>>>(k_weight, o_weight, style, wmod);
    gemm_bt_lds_kernel<float, unsigned short, true><<<1024, 256, 0, stream>>>(x, wmod, kqv, vt);
    attn_kernel<<<1024, 256, 0, stream>>>(kqv, vt, attn);
    gemm_bt_lds_kernel<unsigned short, float, false><<<1024, 256, 0, stream>>>(attn, wmod + (size_t)8 * 512 * 512, out, nullptr);
}